// Round 11
// baseline (222.807 us; speedup 1.0000x reference)
//
#include <hip/hip_runtime.h>
#include <math.h>

#define IMG_H 1024
#define IMG_W 1024
#define IMG_B 8
#define TPB 512                    // 512 thr * 2 px = one full row
#define PXT 2                      // pixels per thread (packed fp32 pairs)
#define RPB 16                     // output rows per band
#define BANDS (IMG_H / RPB)        // 64
#define NBLK (IMG_B * BANDS)       // 512 blocks = 2/CU

typedef float v2f __attribute__((ext_vector_type(2)));

__device__ __forceinline__ float sig2(float x) {   // sigmoid(2x) == sigmoid(x/EPS)
    return 1.0f / (1.0f + __expf(-2.0f * x));
}
__device__ __forceinline__ int imax(int a, int b) { return a > b ? a : b; }
__device__ __forceinline__ int imin(int a, int b) { return a < b ? a : b; }

// ---------------------------------------------------------------------------
// Depth-D row-pipelined kernel, 2 px/thread with PACKED FP32 arithmetic.
// Identical structure/bounds/barriers/LDS to the verified Round-3 kernel;
// the single change is v2f (ext_vector float2) arithmetic so clang emits
// v_pk_{mul,add,fma}_f32 (2 floats per issue slot) for all per-pixel math.
// Scalar remainder: sig2 (exp/rcp have no packed form), fmax, LDS boundary
// scalars (sp stores px1 = .y, su stores px0 = .x).
// ---------------------------------------------------------------------------
template<int D, bool READQ, bool FINAL>
__global__ __launch_bounds__(TPB, 4) void k_pipe(const float* __restrict__ qin,
                                                 const float* __restrict__ vf,
                                                 const float* __restrict__ o,
                                                 float* __restrict__ out) {
    __shared__ float sp[D + 1][TPB + 1];   // p0 boundary (px1 of each thread)
    __shared__ float su[D][2][TPB + 1];    // u boundary (px0), row-parity dbuf

    const int img = blockIdx.x / BANDS;
    const int r0  = (blockIdx.x % BANDS) * RPB;
    const int tid = threadIdx.x;
    const int x0  = tid * PXT;
    const size_t ibase = (size_t)img * IMG_H * IMG_W;

    if (tid == 0) {
#pragma unroll
        for (int l = 0; l <= D; ++l) sp[l][0] = 0.0f;
#pragma unroll
        for (int l = 0; l < D; ++l) { su[l][0][TPB] = 0.0f; su[l][1][TPB] = 0.0f; }
    }

    constexpr int HALO = FINAL ? 1 : 0;
    constexpr int NOH  = FINAL ? D + 1 : D;

    const int u0lo = imax(r0 - (D - 1) - HALO, 0);
    const int ylo  = READQ ? imax(r0 - D - HALO, 0) : u0lo;
    const int yend = r0 + RPB - 1 + D;
    const int yhi  = imin(yend, IMG_H - 1);

    const v2f z2 = {0.0f, 0.0f};
    v2f qc = z2, qz = z2, qvPrev = z2;     // q^0 rows y, y-1; q^l previous
    v2f oh[NOH];                           // o rows y-l
    v2f v0h[D + 1], v1h[D + 1];            // vf rows y-l
    v2f uY[D], uZ[D];                      // u^l rows y-l, y-l-1
    v2f p1prev[D + 1];                     // p1 of q^l at previous row
    v2f qsave[D];                          // q^l held one step for level l+1

#pragma unroll
    for (int l = 0; l < NOH; ++l) oh[l] = z2;
#pragma unroll
    for (int l = 0; l <= D; ++l) { v0h[l] = z2; v1h[l] = z2; p1prev[l] = z2; }
#pragma unroll
    for (int l = 0; l < D; ++l) { uY[l] = z2; uZ[l] = z2; qsave[l] = z2; }

    const float* pQ = qin + ibase + (size_t)ylo * IMG_W + x0;
    const float* pO = o   + ibase + (size_t)ylo * IMG_W + x0;
    const float* pV = vf  + ((size_t)ylo * IMG_W + x0) * 2;

    for (int y = ylo; y <= yend; ++y) {
        // ---- shift row histories, then load row y ----
#pragma unroll
        for (int k = NOH - 1; k >= 1; --k) oh[k] = oh[k - 1];
#pragma unroll
        for (int k = D; k >= 1; --k) { v0h[k] = v0h[k - 1]; v1h[k] = v1h[k - 1]; }
        if constexpr (READQ) qz = qc;

        if (y <= yhi) {
            if constexpr (READQ) {
                float2 q2 = *(const float2*)pQ; pQ += IMG_W;
                qc = (v2f){q2.x, q2.y};
            }
            float2 o2 = *(const float2*)pO; pO += IMG_W;
            oh[0] = (v2f){o2.x, o2.y};
            float4 v4 = *(const float4*)pV; pV += 2 * IMG_W;
            v0h[0] = (v2f){v4.x, v4.z};
            v1h[0] = (v2f){v4.y, v4.w};
        } else {
            qc = z2; oh[0] = z2; v0h[0] = z2; v1h[0] = z2;
        }

        // ---- level 0 ----
        if constexpr (READQ) {
            v2f p0c = v0h[0] * qc;                 // v_pk_mul
            v2f p1c = v1h[0] * qc;
            sp[0][tid + 1] = p0c.y;
            __syncthreads();                       // barrier level 0
            if (y >= u0lo) {
                const float lft = sp[0][tid];
                v2f pl = {lft, p0c.x};
                v2f ar = oh[0] - (p1c - p1prev[0] + p0c - pl);   // packed chain
                v2f nu;
                if (y <= IMG_H - 1) { nu.x = sig2(ar.x); nu.y = sig2(ar.y); }
                else                  nu = z2;
                uZ[0] = uY[0]; uY[0] = nu;
                su[0][y & 1][tid] = nu.x;
            }
            p1prev[0] = p1c;
        } else {
            v2f nu;
            if (y <= IMG_H - 1) { nu.x = sig2(oh[0].x); nu.y = sig2(oh[0].y); }
            else                  nu = z2;
            uZ[0] = uY[0]; uY[0] = nu;
            su[0][y & 1][tid] = nu.x;
        }

        // ---- levels 1..D ----
#pragma unroll
        for (int l = 1; l <= D; ++l) {
            const int t = y - l;
            const int qlo = imax(r0 - (D - l) - HALO, 0);
            const bool qvalid = (t >= qlo) && (t <= IMG_H - 1);
            v2f qb = (l == 1) ? (READQ ? qz : z2) : qsave[l - 1];
            if (l >= 2) qsave[l - 1] = qvPrev;      // delayed save
            v2f qv;
            if (qvalid) {
                const float uRx = su[l - 1][t & 1][tid + 1];
                v2f uR = {uZ[l - 1].y, uRx};
                v2f gy = uY[l - 1] - uZ[l - 1];     // v_pk_add
                v2f gx = uR - uZ[l - 1];
                v2f s  = gy * v1h[l] + gx * v0h[l]; // v_pk_mul + v_pk_fma
                v2f c  = qb - 0.5f * s;             // v_pk_fma
                qv.x = fmaxf(c.x, 0.0f);
                qv.y = fmaxf(c.y, 0.0f);
            } else {
                qv = z2;
            }

            if (l < D) {
                v2f p0p = v0h[l] * qv;
                v2f p1p = v1h[l] * qv;
                sp[l][tid + 1] = p0p.y;
                __syncthreads();                   // barrier level l
                const int ulo = imax(r0 - (D - 1 - l) - HALO, 0);
                if (t >= ulo) {
                    const float lft = sp[l][tid];
                    v2f pl = {lft, p0p.x};
                    v2f ar = oh[l] - (p1p - p1prev[l] + p0p - pl);
                    v2f nu;
                    if (t <= IMG_H - 1) { nu.x = sig2(ar.x); nu.y = sig2(ar.y); }
                    else                  nu = z2;
                    uZ[l] = uY[l]; uY[l] = nu;
                    su[l][t & 1][tid] = nu.x;
                }
                p1prev[l] = p1p;
            } else {
                if constexpr (FINAL) {
                    v2f p0p = v0h[D] * qv;
                    v2f p1p = v1h[D] * qv;
                    sp[D][tid + 1] = p0p.y;
                    __syncthreads();               // barrier final
                    if (t >= r0 && t < r0 + RPB) {
                        const float lft = sp[D][tid];
                        v2f pl = {lft, p0p.x};
                        v2f Tq = p1p - p1prev[D] + p0p - pl;
                        v2f r  = 2.0f * (oh[D] - Tq);
                        *(float2*)(out + ibase + (size_t)t * IMG_W + x0) =
                            make_float2(r.x, r.y);
                    }
                    p1prev[D] = p1p;
                } else {
                    if (t >= r0 && t < r0 + RPB)
                        *(float2*)(out + ibase + (size_t)t * IMG_W + x0) =
                            make_float2(qv.x, qv.y);
                }
            }
            qvPrev = qv;
        }
    }
}

extern "C" void kernel_launch(void* const* d_in, const int* in_sizes, int n_in,
                              void* d_out, int out_size, void* d_ws, size_t ws_size,
                              hipStream_t stream) {
    const float* o  = (const float*)d_in[0];
    const float* vf = (const float*)d_in[1];
    float* qA = (float*)d_ws;

    // iterations 1..5: o,vf -> q5  (no q read)
    k_pipe<5, false, false><<<NBLK, TPB, 0, stream>>>(o, vf, o, qA);
    // iterations 6..10 + final: q5,o,vf -> out
    k_pipe<5, true,  true ><<<NBLK, TPB, 0, stream>>>(qA, vf, o, (float*)d_out);
}